// Round 1
// baseline (1204.650 us; speedup 1.0000x reference)
//
#include <hip/hip_runtime.h>
#include <math.h>

#define NEGV -9000000000000000.0f

__device__ __forceinline__ float wave_sum(float v) {
#pragma unroll
  for (int m = 32; m; m >>= 1) v += __shfl_xor(v, m, 64);
  return v;
}

// y_e = sum_d W[r][e=lane][d] * x[d], x in LDS (broadcast reads)
__device__ __forceinline__ float dotrow(const float* __restrict__ W, int r, int lane,
                                        const float* xbuf) {
  const float* Wr = W + (((size_t)r) << 12) + ((size_t)lane << 6);
  float acc = 0.f;
#pragma unroll
  for (int i = 0; i < 16; ++i) {
    float4 w = *(const float4*)(Wr + 4 * i);
    float4 x = *(const float4*)(xbuf + 4 * i);
    acc = fmaf(w.x, x.x, acc);
    acc = fmaf(w.y, x.y, acc);
    acc = fmaf(w.z, x.z, acc);
    acc = fmaf(w.w, x.w, acc);
  }
  return acc;
}

__device__ __forceinline__ float transform_one(int nb, int r, int lane,
                                               const float* __restrict__ emb,
                                               const float* __restrict__ W, float* xbuf) {
  __syncthreads();
  xbuf[lane] = emb[((size_t)nb << 6) + lane];
  __syncthreads();
  return tanhf(dotrow(W, r, lane, xbuf));
}

// Scores eid's 64 neighbors vs user vector, masked softmax, top-8 (lax.top_k
// tie-break: value desc, index asc), second masked softmax.
__device__ __forceinline__ void score_row(int eid, int lane, float u_e,
                                          const float* __restrict__ emb,
                                          const float* __restrict__ W,
                                          const int* __restrict__ adjE,
                                          const int* __restrict__ adjR, float* xbuf,
                                          int& nbr, int& rel, int seli[8], float wout[8]) {
  nbr = adjE[((size_t)eid << 6) + lane];
  rel = adjR[((size_t)eid << 6) + lane];
  float s_mine = 0.f;
  for (int n = 0; n < 64; ++n) {
    int nb = __shfl(nbr, n, 64);
    int r  = __shfl(rel, n, 64);
    __syncthreads();
    xbuf[lane] = emb[((size_t)nb << 6) + lane];
    __syncthreads();
    float y = tanhf(dotrow(W, r, lane, xbuf));
    float tot = wave_sum(u_e * y);
    if (lane == n) s_mine = tot * (1.0f / 64.0f);
  }
  // masked softmax over 64 neighbors
  float sv = (s_mine == 0.0f) ? NEGV : s_mine;
  float mx = sv;
#pragma unroll
  for (int m = 32; m; m >>= 1) mx = fmaxf(mx, __shfl_xor(mx, m, 64));
  float p = expf(sv - mx);
  float Z = wave_sum(p);
  p /= Z;
  // top-8: iterative butterfly argmax with (value desc, index asc)
  float v = p;
  int vi = lane;
  float selv[8];
#pragma unroll
  for (int j = 0; j < 8; ++j) {
    float bv = v;
    int bi = vi;
#pragma unroll
    for (int m = 1; m < 64; m <<= 1) {
      float ov = __shfl_xor(bv, m, 64);
      int oi = __shfl_xor(bi, m, 64);
      if (ov > bv || (ov == bv && oi < bi)) { bv = ov; bi = oi; }
    }
    selv[j] = bv;
    seli[j] = bi;
    if (lane == bi) v = -__builtin_inff();
  }
  // second masked softmax over the 8 selected
  float m8 = -__builtin_inff();
#pragma unroll
  for (int j = 0; j < 8; ++j) {
    float t = (selv[j] == 0.f) ? NEGV : selv[j];
    selv[j] = t;
    m8 = fmaxf(m8, t);
  }
  float Z8 = 0.f;
#pragma unroll
  for (int j = 0; j < 8; ++j) {
    selv[j] = expf(selv[j] - m8);
    Z8 += selv[j];
  }
#pragma unroll
  for (int j = 0; j < 8; ++j) wout[j] = selv[j] / Z8;
}

__global__ __launch_bounds__(64) void k_user(const int* __restrict__ ui,
                                             const float* __restrict__ emb,
                                             const int* __restrict__ clicked,
                                             const float* __restrict__ numc, int hist,
                                             float* __restrict__ user_emb) {
  int b = blockIdx.x, lane = threadIdx.x;
  int u = ui[b];
  float acc = 0.f;
  for (int h = 0; h < hist; ++h) {
    int it = clicked[u * hist + h];
    acc += emb[((size_t)it << 6) + lane];
  }
  user_emb[((size_t)b << 6) + lane] = acc * (1.0f / numc[u]);
}

__global__ __launch_bounds__(64) void k_hop0(const int* __restrict__ ii,
                                             const float* __restrict__ emb,
                                             const float* __restrict__ W,
                                             const int* __restrict__ adjE,
                                             const int* __restrict__ adjR,
                                             const float* __restrict__ user_emb,
                                             float* __restrict__ s0, int* __restrict__ e1,
                                             float* __restrict__ emb1) {
  __shared__ __align__(16) float xbuf[64];
  int b = blockIdx.x, lane = threadIdx.x;
  int item = ii[b];
  float u_e = user_emb[((size_t)b << 6) + lane];
  int nbr, rel, seli[8];
  float w[8];
  score_row(item, lane, u_e, emb, W, adjE, adjR, xbuf, nbr, rel, seli, w);
#pragma unroll
  for (int j = 0; j < 8; ++j) {
    int nb = __shfl(nbr, seli[j], 64);
    int r  = __shfl(rel, seli[j], 64);
    float y = transform_one(nb, r, lane, emb, W, xbuf);
    emb1[(((size_t)b * 8 + j) << 6) + lane] = y;
    if (lane == 0) {
      e1[b * 8 + j] = nb;
      s0[b * 8 + j] = w[j];
    }
  }
}

__global__ __launch_bounds__(64) void k_hop1(
    const int* __restrict__ ui, const int* __restrict__ ii, const float* __restrict__ emb,
    const float* __restrict__ W, const int* __restrict__ adjE, const int* __restrict__ adjR,
    const float* __restrict__ labels, int np1, const float* __restrict__ user_emb,
    const int* __restrict__ e1, const float* __restrict__ emb1, float* __restrict__ emb1p,
    float* __restrict__ lab1p) {
  __shared__ __align__(16) float xbuf[64];
  int bj = blockIdx.x;
  int b = bj >> 3;
  int lane = threadIdx.x;
  int u = ui[b];
  int item = ii[b];
  int eid = e1[bj];
  float u_e = user_emb[((size_t)b << 6) + lane];
  int nbr, rel, seli[8];
  float w[8];
  score_row(eid, lane, u_e, emb, W, adjE, adjR, xbuf, nbr, rel, seli, w);
  float agg = 0.f, labagg = 0.f;
#pragma unroll
  for (int k = 0; k < 8; ++k) {
    int nb = __shfl(nbr, seli[k], 64);
    int r  = __shfl(rel, seli[k], 64);
    float y = transform_one(nb, r, lane, emb, W, xbuf);
    agg = fmaf(w[k], y, agg);
    float raw2 = labels[(size_t)u * np1 + nb];
    float lab2 = (nb != item) ? raw2 : 0.5f;
    labagg = fmaf(w[k], lab2, labagg);
  }
  float base = emb1[((size_t)bj << 6) + lane];
  emb1p[((size_t)bj << 6) + lane] = fmaxf(fmaf(agg, 0.125f, base), 0.f);
  if (lane == 0) {
    float raw1 = labels[(size_t)u * np1 + eid];
    bool hm = (eid != item);
    float l1 = hm ? raw1 : 0.5f;
    bool reset1 = (raw1 != 0.5f) && hm;
    lab1p[bj] = reset1 ? l1 : labagg;
  }
}

__global__ __launch_bounds__(64) void k_final(const int* __restrict__ ii,
                                              const float* __restrict__ emb,
                                              const float* __restrict__ user_emb,
                                              const float* __restrict__ s0,
                                              const float* __restrict__ emb1,
                                              const float* __restrict__ emb1p,
                                              const float* __restrict__ lab1p,
                                              float* __restrict__ out, int bs) {
  int b = blockIdx.x, lane = threadIdx.x;
  int item = ii[b];
  float ue = user_emb[((size_t)b << 6) + lane];
  float agg = 0.f, aggp = 0.f, lab = 0.f;
#pragma unroll
  for (int j = 0; j < 8; ++j) {
    float s = s0[b * 8 + j];
    agg = fmaf(s, emb1[(((size_t)b * 8 + j) << 6) + lane], agg);
    aggp = fmaf(s, emb1p[(((size_t)b * 8 + j) << 6) + lane], aggp);
    lab = fmaf(s, lab1p[b * 8 + j], lab);
  }
  float e0 = emb[((size_t)item << 6) + lane];
  float h = fmaxf(fmaf(agg, 0.125f, e0), 0.f);   // relu(agg01 + emb0)
  float h2 = tanhf(fmaf(aggp, 0.125f, h));       // tanh(agg01' + emb0')
  float dot = wave_sum(ue * h2);
  if (lane == 0) {
    out[b] = 1.f / (1.f + expf(-dot));
    out[bs + b] = 1.f / (1.f + expf(-(lab - 0.5f)));
  }
}

extern "C" void kernel_launch(void* const* d_in, const int* in_sizes, int n_in, void* d_out,
                              int out_size, void* d_ws, size_t ws_size, hipStream_t stream) {
  const int* ui = (const int*)d_in[0];
  const int* ii = (const int*)d_in[1];
  const float* emb = (const float*)d_in[2];
  const float* W = (const float*)d_in[3];
  const int* adjE = (const int*)d_in[4];
  const int* adjR = (const int*)d_in[5];
  const int* clicked = (const int*)d_in[6];
  const float* numc = (const float*)d_in[7];
  const float* labels = (const float*)d_in[8];

  int bs = in_sizes[0];
  int np1 = in_sizes[2] / 64;      // n_entity + 1 (= labels row stride = offset)
  int nuser = in_sizes[7];
  int hist = in_sizes[6] / nuser;

  float* user_emb = (float*)d_ws;                    // bs*64
  float* s0 = user_emb + (size_t)bs * 64;            // bs*8
  int* e1 = (int*)(s0 + (size_t)bs * 8);             // bs*8
  float* lab1p = (float*)(e1 + (size_t)bs * 8);      // bs*8
  float* emb1 = lab1p + (size_t)bs * 8;              // bs*8*64
  float* emb1p = emb1 + (size_t)bs * 8 * 64;         // bs*8*64

  k_user<<<bs, 64, 0, stream>>>(ui, emb, clicked, numc, hist, user_emb);
  k_hop0<<<bs, 64, 0, stream>>>(ii, emb, W, adjE, adjR, user_emb, s0, e1, emb1);
  k_hop1<<<bs * 8, 64, 0, stream>>>(ui, ii, emb, W, adjE, adjR, labels, np1, user_emb, e1,
                                    emb1, emb1p, lab1p);
  k_final<<<bs, 64, 0, stream>>>(ii, emb, user_emb, s0, emb1, emb1p, lab1p, (float*)d_out,
                                 bs);
}